// Round 9
// baseline (397.398 us; speedup 1.0000x reference)
//
#include <hip/hip_runtime.h>
#include <hip/hip_bf16.h>
#include <stdint.h>

typedef __attribute__((ext_vector_type(8))) short bf16x8;
typedef __attribute__((ext_vector_type(4))) float f32x4;
typedef __attribute__((ext_vector_type(16))) float f32x16;
typedef __attribute__((ext_vector_type(4))) unsigned u32x4;

#define L2E 1.4426950408889634f

static __device__ __forceinline__ unsigned short f2bf(float f) {
    __hip_bfloat16 h = __float2bfloat16(f);
    return __builtin_bit_cast(unsigned short, h);
}

static __device__ __forceinline__ void gl2lds16(const void* g, void* l) {
    __builtin_amdgcn_global_load_lds(
        (const __attribute__((address_space(1))) void*)g,
        (__attribute__((address_space(3))) void*)l,
        16, 0, 0);
}

// ---------------- cast fp32 -> bf16 ----------------
__global__ void cast_kernel(const float* __restrict__ src,
                            unsigned short* __restrict__ dst, int n4) {
    int i = blockIdx.x * blockDim.x + threadIdx.x;
    int stride = gridDim.x * blockDim.x;
    for (; i < n4; i += stride) {
        float4 v = ((const float4*)src)[i];
        ushort4 o;
        o.x = f2bf(v.x); o.y = f2bf(v.y); o.z = f2bf(v.z); o.w = f2bf(v.w);
        ((ushort4*)dst)[i] = o;
    }
}

// 4 weight matrices (1M elems each) in one dispatch; grid (256, 4)
__global__ void cast4_kernel(const float* __restrict__ s0, const float* __restrict__ s1,
                             const float* __restrict__ s2, const float* __restrict__ s3,
                             unsigned short* __restrict__ d0, unsigned short* __restrict__ d1,
                             unsigned short* __restrict__ d2, unsigned short* __restrict__ d3) {
    const int m = blockIdx.y;
    const float* src = m == 0 ? s0 : m == 1 ? s1 : m == 2 ? s2 : s3;
    unsigned short* dst = m == 0 ? d0 : m == 1 ? d1 : m == 2 ? d2 : d3;
    int i = blockIdx.x * blockDim.x + threadIdx.x;
    for (; i < 262144; i += 256 * 256) {
        float4 v = ((const float4*)src)[i];
        ushort4 o;
        o.x = f2bf(v.x); o.y = f2bf(v.y); o.z = f2bf(v.z); o.w = f2bf(v.w);
        ((ushort4*)dst)[i] = o;
    }
}

// ---------------- fused QKV projection GEMM ----------------
__global__ __launch_bounds__(256) void qkv_gemm(
    const unsigned short* __restrict__ A,
    const unsigned short* __restrict__ Wq,
    const unsigned short* __restrict__ Wk,
    const unsigned short* __restrict__ Wv,
    const float* __restrict__ bq,
    const float* __restrict__ bk,
    const float* __restrict__ bv,
    const float* __restrict__ ocr,
    float qscale,
    unsigned short* __restrict__ Qo,
    unsigned short* __restrict__ Ko,
    unsigned short* __restrict__ VTo)
{
    constexpr int K = 1024;
    __shared__ __align__(16) unsigned short SMEM[16384];   // 32 KB, reused in epilogue
    unsigned short (*As)[64] = (unsigned short(*)[64])SMEM;
    unsigned short (*Bs)[64] = (unsigned short(*)[64])(SMEM + 8192);

    const int tid  = threadIdx.x;
    const int wave = tid >> 6, lane = tid & 63;
    const int li = lane & 15, lg = lane >> 4;

    const int lin = blockIdx.y * 24 + blockIdx.x;
    const int n2  = (lin & 7) * 192 + (lin >> 3);   // XCD-chunked, bijective
    const int mb = n2 / 24, nbb = n2 - mb * 24;
    const int proj = nbb >> 3;
    const int m0 = mb * 128, n0 = (nbb & 7) * 128;

    const unsigned short* W = proj == 0 ? Wq : proj == 1 ? Wk : Wv;
    const float* bias = proj == 0 ? bq : proj == 1 ? bk : bv;

    const int wm = (wave >> 1) * 64, wn = (wave & 1) * 64;
    const int srow = wave * 8 + (lane >> 3);
    const int scol = (lane & 7) * 8;

    f32x4 acc[4][4] = {};

    for (int k0 = 0; k0 < K; k0 += 64) {
#pragma unroll
        for (int rnd = 0; rnd < 4; ++rnd)
            gl2lds16(A + (size_t)(m0 + rnd * 32 + srow) * K + k0 + scol,
                     &As[rnd * 32 + wave * 8][0]);
#pragma unroll
        for (int rnd = 0; rnd < 4; ++rnd)
            gl2lds16(W + (size_t)(n0 + rnd * 32 + srow) * K + k0 + scol,
                     &Bs[rnd * 32 + wave * 8][0]);
        __syncthreads();
#pragma unroll
        for (int kk = 0; kk < 64; kk += 32) {
            bf16x8 af[4], bfr[4];
#pragma unroll
            for (int m = 0; m < 4; ++m)
                af[m] = *(const bf16x8*)&As[wm + m * 16 + li][kk + lg * 8];
#pragma unroll
            for (int n = 0; n < 4; ++n)
                bfr[n] = *(const bf16x8*)&Bs[wn + n * 16 + li][kk + lg * 8];
#pragma unroll
            for (int m = 0; m < 4; ++m)
#pragma unroll
                for (int n = 0; n < 4; ++n)
                    acc[m][n] = __builtin_amdgcn_mfma_f32_16x16x32_bf16(
                        af[m], bfr[n], acc[m][n], 0, 0, 0);
        }
        __syncthreads();
    }

    if (proj == 2) {
#pragma unroll
        for (int n = 0; n < 4; ++n) {
            const int dl = wn + n * 16 + li;
            const float bb = bias[n0 + dl];
#pragma unroll
            for (int m = 0; m < 4; ++m) {
                const int sl = wm + m * 16 + lg * 4;
                const int unit = (sl >> 2) ^ (dl & 7);
                ushort4 o;
                o.x = f2bf(acc[m][n][0] + bb);
                o.y = f2bf(acc[m][n][1] + bb);
                o.z = f2bf(acc[m][n][2] + bb);
                o.w = f2bf(acc[m][n][3] + bb);
                *(ushort4*)&SMEM[dl * 128 + unit * 4] = o;
            }
        }
        __syncthreads();
        const int s2 = (lane & 15) * 8;
        const int u0b = s2 >> 2;
#pragma unroll
        for (int k = 0; k < 8; ++k) {
            const int dl = wave * 32 + k * 4 + (lane >> 4);
            const int u0 = u0b ^ (dl & 7);
            const int u1 = (u0b + 1) ^ (dl & 7);
            uint2 lo = *(uint2*)&SMEM[dl * 128 + u0 * 4];
            uint2 hi = *(uint2*)&SMEM[dl * 128 + u1 * 4];
            const int col = n0 + dl;
            const int bh2 = ((m0 >> 11) << 4) + (col >> 6);
            uint4 o4;
            o4.x = lo.x; o4.y = lo.y; o4.z = hi.x; o4.w = hi.y;
            *(uint4*)&VTo[((size_t)bh2 * 64 + (col & 63)) * 2048 + (m0 & 2047) + s2] = o4;
        }
    } else {
        const float scale = proj == 0 ? qscale : 1.f;
        unsigned short* dst = proj == 0 ? Qo : Ko;
#pragma unroll
        for (int n = 0; n < 4; ++n) {
            const int col = n0 + wn + n * 16 + li;
            float bb = bias[col];
            if (proj == 0) bb += ocr[col];
#pragma unroll
            for (int m = 0; m < 4; ++m)
#pragma unroll
                for (int r = 0; r < 4; ++r) {
                    const int row = m0 + wm + m * 16 + lg * 4 + r;
                    dst[(size_t)row * 1024 + col] = f2bf((acc[m][n][r] + bb) * scale);
                }
        }
    }
}

// ---------------- output projection GEMM (f32 out) ----------------
__global__ __launch_bounds__(256) void out_gemm(
    const unsigned short* __restrict__ A,
    const unsigned short* __restrict__ W,
    const float* __restrict__ bias,
    float* __restrict__ of)
{
    constexpr int K = 1024;
    __shared__ unsigned short As[128][64];
    __shared__ unsigned short Bs[128][64];

    const int tid  = threadIdx.x;
    const int wave = tid >> 6, lane = tid & 63;
    const int li = lane & 15, lg = lane >> 4;
    const int lin = blockIdx.y * 8 + blockIdx.x;
    const int n2  = (lin & 7) * 64 + (lin >> 3);
    const int m0 = (n2 >> 3) * 128, n0 = (n2 & 7) * 128;
    const int wm = (wave >> 1) * 64, wn = (wave & 1) * 64;

    const int srow = wave * 8 + (lane >> 3);
    const int scol = (lane & 7) * 8;

    f32x4 acc[4][4] = {};

    for (int k0 = 0; k0 < K; k0 += 64) {
#pragma unroll
        for (int rnd = 0; rnd < 4; ++rnd)
            gl2lds16(A + (size_t)(m0 + rnd * 32 + srow) * K + k0 + scol,
                     &As[rnd * 32 + wave * 8][0]);
#pragma unroll
        for (int rnd = 0; rnd < 4; ++rnd)
            gl2lds16(W + (size_t)(n0 + rnd * 32 + srow) * K + k0 + scol,
                     &Bs[rnd * 32 + wave * 8][0]);
        __syncthreads();
#pragma unroll
        for (int kk = 0; kk < 64; kk += 32) {
            bf16x8 af[4], bfr[4];
#pragma unroll
            for (int m = 0; m < 4; ++m)
                af[m] = *(const bf16x8*)&As[wm + m * 16 + li][kk + lg * 8];
#pragma unroll
            for (int n = 0; n < 4; ++n)
                bfr[n] = *(const bf16x8*)&Bs[wn + n * 16 + li][kk + lg * 8];
#pragma unroll
            for (int m = 0; m < 4; ++m)
#pragma unroll
                for (int n = 0; n < 4; ++n)
                    acc[m][n] = __builtin_amdgcn_mfma_f32_16x16x32_bf16(
                        af[m], bfr[n], acc[m][n], 0, 0, 0);
        }
        __syncthreads();
    }

#pragma unroll
    for (int n = 0; n < 4; ++n) {
        const int col = n0 + wn + n * 16 + li;
        const float bb = bias[col];
#pragma unroll
        for (int m = 0; m < 4; ++m)
#pragma unroll
            for (int r = 0; r < 4; ++r) {
                const int row = m0 + wm + m * 16 + lg * 4 + r;
                of[(size_t)row * 1024 + col] = acc[m][n][r] + bb;
            }
    }
}

// ---------------- fused flash attention (32x32x16, PV pipelined 1 behind) ---
// Same schedule as round 8 but the per-tile body is a template<int U>
// __forceinline__ function: clang MUST inline (always_inline), so pw/acc/qf
// stay in VGPRs (round-8 failure: outlined lambda -> captures in scratch).
template<int U>
static __device__ __forceinline__ void attn_iter(
    int t_,
    unsigned short (*Ks)[4096], unsigned short (*Vs)[4096],
    const unsigned short* Kg0, const unsigned short* Vg0,
    int w, int li5, int l5, int li7, int qb, int qrow,
    const bf16x8 (&qf)[4], f32x16 (&acc)[2],
    float& ls0, float& ls1, float& ls2, float& ls3,
    unsigned (&pw)[2][2][8])
{
    const int j0 = t_ * 64;
    if (t_ < 31) {
        const int j1 = j0 + 64;
#pragma unroll
        for (int it = 0; it < 2; ++it) {
            gl2lds16(Kg0 + (size_t)(j1 + it * 8) * 1024,
                     &Ks[(U + 1) & 1][(w * 2 + it) * 512]);
            gl2lds16(Vg0 + (size_t)(it * 8) * 2048 + j1,
                     &Vs[(U + 1) & 3][(w * 2 + it) * 512]);
        }
    }

    // QK^T: st[jf][reg] = S[q=li5][j = j0 + jf*32 + (reg&3) + 8*(reg>>2) + 4*l5]
    f32x16 st[2];
    __builtin_amdgcn_s_setprio(1);
#pragma unroll
    for (int jf = 0; jf < 2; ++jf) {
        f32x16 z = {};
#pragma unroll
        for (int f = 0; f < 4; ++f) {
            bf16x8 kf = *(const bf16x8*)&Ks[U & 1][(jf * 32 + li5) * 64
                                                   + ((f * 2 + l5) ^ li7) * 8];
            z = __builtin_amdgcn_mfma_f32_32x32x16_bf16(kf, qf[f], z, 0, 0, 0);
        }
        st[jf] = z;
    }
    __builtin_amdgcn_s_setprio(0);

    if (j0 >= qb - 65 && j0 <= qb + 33) {
#pragma unroll
        for (int jf = 0; jf < 2; ++jf)
#pragma unroll
            for (int r = 0; r < 16; ++r) {
                int j = j0 + jf * 32 + (r & 3) + 8 * (r >> 2) + 4 * l5;
                int dq = qrow - j;
                if ((unsigned)(dq + 2) <= 4u) st[jf][r] += 0.1f * L2E;
            }
    }

    // exp2 + cvt_pk pack into generation U&1
#pragma unroll
    for (int jf = 0; jf < 2; ++jf)
#pragma unroll
        for (int m = 0; m < 8; ++m) {
            float p0 = __builtin_amdgcn_exp2f(st[jf][2 * m]);
            float p1 = __builtin_amdgcn_exp2f(st[jf][2 * m + 1]);
            float pp = p0 + p1;
            if (m & 2) { if (m & 1) ls3 += pp; else ls2 += pp; }
            else       { if (m & 1) ls1 += pp; else ls0 += pp; }
            asm("v_cvt_pk_bf16_f32 %0, %1, %2"
                : "=v"(pw[U & 1][jf][m]) : "v"(p0), "v"(p1));
        }

    // single-transposition redistribution: 8 x permlane32_swap
#pragma unroll
    for (int jf = 0; jf < 2; ++jf)
#pragma unroll
        for (int m2 = 0; m2 < 2; ++m2)
#pragma unroll
            for (int m0_ = 0; m0_ < 2; ++m0_) {
                unsigned a0 = pw[U & 1][jf][m2 * 4 + m0_];
                unsigned b0 = pw[U & 1][jf][m2 * 4 + m0_ + 2];
                asm volatile("v_permlane32_swap_b32 %0, %1"
                             : "+v"(a0), "+v"(b0));
                pw[U & 1][jf][m2 * 4 + m0_]     = a0;
                pw[U & 1][jf][m2 * 4 + m0_ + 2] = b0;
            }

    // PV for tile t_-1: pw generation (U+1)&1, V ring slot (U+3)&3
    if (t_ > 0) {
        __builtin_amdgcn_s_setprio(1);
#pragma unroll
        for (int db = 0; db < 2; ++db)
#pragma unroll
            for (int tt = 0; tt < 4; ++tt) {
                bf16x8 vf = *(const bf16x8*)&Vs[(U + 3) & 3][(db * 32 + li5) * 64
                                                             + ((tt * 2 + l5) ^ li7) * 8];
                const int jf = tt >> 1, m2 = tt & 1;
                u32x4 tw;
                tw.x = pw[(U + 1) & 1][jf][m2 * 4 + 0];
                tw.y = pw[(U + 1) & 1][jf][m2 * 4 + 1];
                tw.z = pw[(U + 1) & 1][jf][m2 * 4 + 2];
                tw.w = pw[(U + 1) & 1][jf][m2 * 4 + 3];
                acc[db] = __builtin_amdgcn_mfma_f32_32x32x16_bf16(
                    vf, __builtin_bit_cast(bf16x8, tw), acc[db], 0, 0, 0);
            }
        __builtin_amdgcn_s_setprio(0);
    }
    __syncthreads();
}

__global__ __launch_bounds__(256, 3) void attn_kernel(
    const unsigned short* __restrict__ Q,
    const unsigned short* __restrict__ Km,
    const unsigned short* __restrict__ VT,
    unsigned short* __restrict__ AO)
{
    __shared__ unsigned short Ks[2][4096];      // [buf][64 j][64 d] 16B-chunk XOR-swz
    __shared__ unsigned short Vs[4][4096];      // ring [slot][64 d][64 j] XOR-swz

    const int tid  = threadIdx.x;
    const int w = tid >> 6, lane = tid & 63;
    const int li5 = lane & 31, l5 = lane >> 5, li7 = li5 & 7;

    // XCD-chunked swizzle over 1024 blocks (16 x 64 grid)
    const int p  = blockIdx.y * 16 + blockIdx.x;
    const int q_ = (p & 7) * 128 + (p >> 3);
    const int bx = q_ & 15, bh = q_ >> 4;
    const int b = bh >> 4, h = bh & 15;
    const int qb = bx * 128 + w * 32;
    const int qrow = qb + li5;

    const int srow = w * 16 + (lane >> 3);
    const int swz  = ((lane & 7) ^ (lane >> 3)) * 8;

    const unsigned short* Kg0 = Km + (size_t)(b * 2048 + srow) * 1024 + h * 64 + swz;
    const unsigned short* Vg0 = VT + ((size_t)bh * 64 + srow) * 2048 + swz;

    bf16x8 qf[4];
#pragma unroll
    for (int f = 0; f < 4; ++f)
        qf[f] = *(const bf16x8*)&Q[(size_t)(b * 2048 + qrow) * 1024 + h * 64
                                   + f * 16 + l5 * 8];

    f32x16 acc[2] = {};
    float ls0 = 0.f, ls1 = 0.f, ls2 = 0.f, ls3 = 0.f;
    unsigned pw[2][2][8];    // [gen][jf][m], gen always static

#pragma unroll
    for (int it = 0; it < 2; ++it) {
        gl2lds16(Kg0 + (size_t)(it * 8) * 1024, &Ks[0][(w * 2 + it) * 512]);
        gl2lds16(Vg0 + (size_t)(it * 8) * 2048, &Vs[0][(w * 2 + it) * 512]);
    }
    __syncthreads();

#pragma unroll 1
    for (int i = 0; i < 8; ++i) {
        const int t4 = i * 4;
        attn_iter<0>(t4 + 0, Ks, Vs, Kg0, Vg0, w, li5, l5, li7, qb, qrow,
                     qf, acc, ls0, ls1, ls2, ls3, pw);
        attn_iter<1>(t4 + 1, Ks, Vs, Kg0, Vg0, w, li5, l5, li7, qb, qrow,
                     qf, acc, ls0, ls1, ls2, ls3, pw);
        attn_iter<2>(t4 + 2, Ks, Vs, Kg0, Vg0, w, li5, l5, li7, qb, qrow,
                     qf, acc, ls0, ls1, ls2, ls3, pw);
        attn_iter<3>(t4 + 3, Ks, Vs, Kg0, Vg0, w, li5, l5, li7, qb, qrow,
                     qf, acc, ls0, ls1, ls2, ls3, pw);
    }

    // drain: PV(31) -- pw gen 1, V ring slot 3
    __builtin_amdgcn_s_setprio(1);
#pragma unroll
    for (int db = 0; db < 2; ++db)
#pragma unroll
        for (int tt = 0; tt < 4; ++tt) {
            bf16x8 vf = *(const bf16x8*)&Vs[3][(db * 32 + li5) * 64
                                             + ((tt * 2 + l5) ^ li7) * 8];
            const int jf = tt >> 1, m2 = tt & 1;
            u32x4 tw;
            tw.x = pw[1][jf][m2 * 4 + 0];
            tw.y = pw[1][jf][m2 * 4 + 1];
            tw.z = pw[1][jf][m2 * 4 + 2];
            tw.w = pw[1][jf][m2 * 4 + 3];
            acc[db] = __builtin_amdgcn_mfma_f32_32x32x16_bf16(
                vf, __builtin_bit_cast(bf16x8, tw), acc[db], 0, 0, 0);
        }
    __builtin_amdgcn_s_setprio(0);

    float lr = (ls0 + ls1) + (ls2 + ls3);
    float l2 = lr + __shfl_xor(lr, 32);
    const float inv = 1.f / l2;
#pragma unroll
    for (int db = 0; db < 2; ++db)
#pragma unroll
        for (int g = 0; g < 4; ++g) {
            ushort4 o;
            o.x = f2bf(acc[db][g * 4 + 0] * inv);
            o.y = f2bf(acc[db][g * 4 + 1] * inv);
            o.z = f2bf(acc[db][g * 4 + 2] * inv);
            o.w = f2bf(acc[db][g * 4 + 3] * inv);
            *(ushort4*)&AO[(size_t)(b * 2048 + qrow) * 1024 + h * 64
                           + db * 32 + g * 8 + l5 * 4] = o;
        }
}

// ---------------- launch ----------------
extern "C" void kernel_launch(void* const* d_in, const int* in_sizes, int n_in,
                              void* d_out, int out_size, void* d_ws, size_t ws_size,
                              hipStream_t stream) {
    const float* x   = (const float*)d_in[0];
    const float* Wq  = (const float*)d_in[2];
    const float* bq  = (const float*)d_in[3];
    const float* Wk  = (const float*)d_in[4];
    const float* bk  = (const float*)d_in[5];
    const float* Wv  = (const float*)d_in[6];
    const float* bv  = (const float*)d_in[7];
    const float* Wo  = (const float*)d_in[8];
    const float* bo  = (const float*)d_in[9];
    const float* ocr = (const float*)d_in[10];
    float* out = (float*)d_out;

    char* ws = (char*)d_ws;
    const size_t MB = 1024 * 1024;
    unsigned short* xb  = (unsigned short*)(ws);            // 16 MB (reused as AO)
    unsigned short* Wqb = (unsigned short*)(ws + 16 * MB);  // 2 MB each
    unsigned short* Wkb = (unsigned short*)(ws + 18 * MB);
    unsigned short* Wvb = (unsigned short*)(ws + 20 * MB);
    unsigned short* Wob = (unsigned short*)(ws + 22 * MB);
    unsigned short* Qb  = (unsigned short*)(ws + 24 * MB);  // 16 MB
    unsigned short* Kb  = (unsigned short*)(ws + 40 * MB);  // 16 MB
    unsigned short* VTb = (unsigned short*)(ws + 56 * MB);  // 16 MB, [bh][d][s]
    unsigned short* AO  = xb;  // x dead after projections

    cast_kernel<<<2048, 256, 0, stream>>>(x, xb, 8388608 / 4);
    cast4_kernel<<<dim3(256, 4), 256, 0, stream>>>(Wq, Wk, Wv, Wo,
                                                   Wqb, Wkb, Wvb, Wob);

    const float QSC = 0.125f * L2E;  // fold 1/sqrt(64) and log2(e) into Q
    qkv_gemm<<<dim3(24, 64), 256, 0, stream>>>(xb, Wqb, Wkb, Wvb,
                                               bq, bk, bv, ocr, QSC,
                                               Qb, Kb, VTb);

    attn_kernel<<<dim3(16, 64), 256, 0, stream>>>(Qb, Kb, VTb, AO);

    out_gemm<<<dim3(8, 64), 256, 0, stream>>>(AO, Wob, bo, out);
}

// Round 10
// 295.048 us; speedup vs baseline: 1.3469x; 1.3469x over previous
//
#include <hip/hip_runtime.h>
#include <hip/hip_bf16.h>
#include <stdint.h>

typedef __attribute__((ext_vector_type(8))) short bf16x8;
typedef __attribute__((ext_vector_type(4))) float f32x4;
typedef __attribute__((ext_vector_type(16))) float f32x16;
typedef __attribute__((ext_vector_type(4))) unsigned u32x4;

#define L2E 1.4426950408889634f

static __device__ __forceinline__ unsigned short f2bf(float f) {
    __hip_bfloat16 h = __float2bfloat16(f);
    return __builtin_bit_cast(unsigned short, h);
}

static __device__ __forceinline__ void gl2lds16(const void* g, void* l) {
    __builtin_amdgcn_global_load_lds(
        (const __attribute__((address_space(1))) void*)g,
        (__attribute__((address_space(3))) void*)l,
        16, 0, 0);
}

// ---------------- all casts fp32 -> bf16, one dispatch ----------------
// x (2097152 float4) + 4 weight matrices (262144 float4 each).
__global__ void cast_all(const float* __restrict__ x,
                         const float* __restrict__ Wq, const float* __restrict__ Wk,
                         const float* __restrict__ Wv, const float* __restrict__ Wo,
                         unsigned short* __restrict__ xb,
                         unsigned short* __restrict__ Wqb, unsigned short* __restrict__ Wkb,
                         unsigned short* __restrict__ Wvb, unsigned short* __restrict__ Wob) {
    int i = blockIdx.x * blockDim.x + threadIdx.x;
    const int stride = gridDim.x * blockDim.x;
    for (; i < 3145728; i += stride) {
        const float* src; unsigned short* dst; int k;
        if (i < 2097152) { src = x; dst = xb; k = i; }
        else {
            int j = i - 2097152; int m = j >> 18; k = j & 262143;
            src = m == 0 ? Wq : m == 1 ? Wk : m == 2 ? Wv : Wo;
            dst = m == 0 ? Wqb : m == 1 ? Wkb : m == 2 ? Wvb : Wob;
        }
        float4 v = ((const float4*)src)[k];
        ushort4 o;
        o.x = f2bf(v.x); o.y = f2bf(v.y); o.z = f2bf(v.z); o.w = f2bf(v.w);
        ((ushort4*)dst)[k] = o;
    }
}

// ---------------- fused QKV projection GEMM ----------------
__global__ __launch_bounds__(256) void qkv_gemm(
    const unsigned short* __restrict__ A,
    const unsigned short* __restrict__ Wq,
    const unsigned short* __restrict__ Wk,
    const unsigned short* __restrict__ Wv,
    const float* __restrict__ bq,
    const float* __restrict__ bk,
    const float* __restrict__ bv,
    const float* __restrict__ ocr,
    float qscale,
    unsigned short* __restrict__ Qo,
    unsigned short* __restrict__ Ko,
    unsigned short* __restrict__ VTo)
{
    constexpr int K = 1024;
    __shared__ __align__(16) unsigned short SMEM[16384];   // 32 KB, reused in epilogue
    unsigned short (*As)[64] = (unsigned short(*)[64])SMEM;
    unsigned short (*Bs)[64] = (unsigned short(*)[64])(SMEM + 8192);

    const int tid  = threadIdx.x;
    const int wave = tid >> 6, lane = tid & 63;
    const int li = lane & 15, lg = lane >> 4;

    const int lin = blockIdx.y * 24 + blockIdx.x;
    const int n2  = (lin & 7) * 192 + (lin >> 3);   // XCD-chunked, bijective
    const int mb = n2 / 24, nbb = n2 - mb * 24;
    const int proj = nbb >> 3;
    const int m0 = mb * 128, n0 = (nbb & 7) * 128;

    const unsigned short* W = proj == 0 ? Wq : proj == 1 ? Wk : Wv;
    const float* bias = proj == 0 ? bq : proj == 1 ? bk : bv;

    const int wm = (wave >> 1) * 64, wn = (wave & 1) * 64;
    const int srow = wave * 8 + (lane >> 3);
    const int scol = (lane & 7) * 8;

    f32x4 acc[4][4] = {};

    for (int k0 = 0; k0 < K; k0 += 64) {
#pragma unroll
        for (int rnd = 0; rnd < 4; ++rnd)
            gl2lds16(A + (size_t)(m0 + rnd * 32 + srow) * K + k0 + scol,
                     &As[rnd * 32 + wave * 8][0]);
#pragma unroll
        for (int rnd = 0; rnd < 4; ++rnd)
            gl2lds16(W + (size_t)(n0 + rnd * 32 + srow) * K + k0 + scol,
                     &Bs[rnd * 32 + wave * 8][0]);
        __syncthreads();
#pragma unroll
        for (int kk = 0; kk < 64; kk += 32) {
            bf16x8 af[4], bfr[4];
#pragma unroll
            for (int m = 0; m < 4; ++m)
                af[m] = *(const bf16x8*)&As[wm + m * 16 + li][kk + lg * 8];
#pragma unroll
            for (int n = 0; n < 4; ++n)
                bfr[n] = *(const bf16x8*)&Bs[wn + n * 16 + li][kk + lg * 8];
#pragma unroll
            for (int m = 0; m < 4; ++m)
#pragma unroll
                for (int n = 0; n < 4; ++n)
                    acc[m][n] = __builtin_amdgcn_mfma_f32_16x16x32_bf16(
                        af[m], bfr[n], acc[m][n], 0, 0, 0);
        }
        __syncthreads();
    }

    if (proj == 2) {
#pragma unroll
        for (int n = 0; n < 4; ++n) {
            const int dl = wn + n * 16 + li;
            const float bb = bias[n0 + dl];
#pragma unroll
            for (int m = 0; m < 4; ++m) {
                const int sl = wm + m * 16 + lg * 4;
                const int unit = (sl >> 2) ^ (dl & 7);
                ushort4 o;
                o.x = f2bf(acc[m][n][0] + bb);
                o.y = f2bf(acc[m][n][1] + bb);
                o.z = f2bf(acc[m][n][2] + bb);
                o.w = f2bf(acc[m][n][3] + bb);
                *(ushort4*)&SMEM[dl * 128 + unit * 4] = o;
            }
        }
        __syncthreads();
        const int s2 = (lane & 15) * 8;
        const int u0b = s2 >> 2;
#pragma unroll
        for (int k = 0; k < 8; ++k) {
            const int dl = wave * 32 + k * 4 + (lane >> 4);
            const int u0 = u0b ^ (dl & 7);
            const int u1 = (u0b + 1) ^ (dl & 7);
            uint2 lo = *(uint2*)&SMEM[dl * 128 + u0 * 4];
            uint2 hi = *(uint2*)&SMEM[dl * 128 + u1 * 4];
            const int col = n0 + dl;
            const int bh2 = ((m0 >> 11) << 4) + (col >> 6);
            uint4 o4;
            o4.x = lo.x; o4.y = lo.y; o4.z = hi.x; o4.w = hi.y;
            *(uint4*)&VTo[((size_t)bh2 * 64 + (col & 63)) * 2048 + (m0 & 2047) + s2] = o4;
        }
    } else {
        const float scale = proj == 0 ? qscale : 1.f;
        unsigned short* dst = proj == 0 ? Qo : Ko;
#pragma unroll
        for (int n = 0; n < 4; ++n) {
            const int col = n0 + wn + n * 16 + li;
            float bb = bias[col];
            if (proj == 0) bb += ocr[col];
#pragma unroll
            for (int m = 0; m < 4; ++m)
#pragma unroll
                for (int r = 0; r < 4; ++r) {
                    const int row = m0 + wm + m * 16 + lg * 4 + r;
                    dst[(size_t)row * 1024 + col] = f2bf((acc[m][n][r] + bb) * scale);
                }
        }
    }
}

// ---------------- output projection GEMM (f32 out) ----------------
__global__ __launch_bounds__(256) void out_gemm(
    const unsigned short* __restrict__ A,
    const unsigned short* __restrict__ W,
    const float* __restrict__ bias,
    float* __restrict__ of)
{
    constexpr int K = 1024;
    __shared__ unsigned short As[128][64];
    __shared__ unsigned short Bs[128][64];

    const int tid  = threadIdx.x;
    const int wave = tid >> 6, lane = tid & 63;
    const int li = lane & 15, lg = lane >> 4;
    const int lin = blockIdx.y * 8 + blockIdx.x;
    const int n2  = (lin & 7) * 64 + (lin >> 3);
    const int m0 = (n2 >> 3) * 128, n0 = (n2 & 7) * 128;
    const int wm = (wave >> 1) * 64, wn = (wave & 1) * 64;

    const int srow = wave * 8 + (lane >> 3);
    const int scol = (lane & 7) * 8;

    f32x4 acc[4][4] = {};

    for (int k0 = 0; k0 < K; k0 += 64) {
#pragma unroll
        for (int rnd = 0; rnd < 4; ++rnd)
            gl2lds16(A + (size_t)(m0 + rnd * 32 + srow) * K + k0 + scol,
                     &As[rnd * 32 + wave * 8][0]);
#pragma unroll
        for (int rnd = 0; rnd < 4; ++rnd)
            gl2lds16(W + (size_t)(n0 + rnd * 32 + srow) * K + k0 + scol,
                     &Bs[rnd * 32 + wave * 8][0]);
        __syncthreads();
#pragma unroll
        for (int kk = 0; kk < 64; kk += 32) {
            bf16x8 af[4], bfr[4];
#pragma unroll
            for (int m = 0; m < 4; ++m)
                af[m] = *(const bf16x8*)&As[wm + m * 16 + li][kk + lg * 8];
#pragma unroll
            for (int n = 0; n < 4; ++n)
                bfr[n] = *(const bf16x8*)&Bs[wn + n * 16 + li][kk + lg * 8];
#pragma unroll
            for (int m = 0; m < 4; ++m)
#pragma unroll
                for (int n = 0; n < 4; ++n)
                    acc[m][n] = __builtin_amdgcn_mfma_f32_16x16x32_bf16(
                        af[m], bfr[n], acc[m][n], 0, 0, 0);
        }
        __syncthreads();
    }

#pragma unroll
    for (int n = 0; n < 4; ++n) {
        const int col = n0 + wn + n * 16 + li;
        const float bb = bias[col];
#pragma unroll
        for (int m = 0; m < 4; ++m)
#pragma unroll
            for (int r = 0; r < 4; ++r) {
                const int row = m0 + wm + m * 16 + lg * 4 + r;
                of[(size_t)row * 1024 + col] = acc[m][n][r] + bb;
            }
    }
}

// ---------------- fused flash attention (32x32x16, 2 q-sets, 2 tiles/barrier)
// Round-6 structure (known spill-free) with HALF the barriers: each iteration
// stages 128 j-cols (2 tiles) double-buffered and computes both sub-tiles
// between barriers. No register state added across the barrier (pw/st stay
// tile-local -- the spill-safe property rounds 7-9 violated).
__global__ __launch_bounds__(256, 2) void attn_kernel(
    const unsigned short* __restrict__ Q,
    const unsigned short* __restrict__ Km,
    const unsigned short* __restrict__ VT,
    unsigned short* __restrict__ AO)
{
    __shared__ unsigned short Ks[2][8192];      // [dbuf][2 tiles][64 j][64 d] swz
    __shared__ unsigned short Vs[2][8192];      // [dbuf][2 tiles][64 d][64 j] swz

    const int tid  = threadIdx.x;
    const int w = tid >> 6, lane = tid & 63;
    const int li5 = lane & 31, l5 = lane >> 5, li7 = li5 & 7;

    // bijective XCD-chunked remap over 512 blocks (8 x 64 grid)
    const int p  = blockIdx.y * 8 + blockIdx.x;
    const int q_ = (p & 7) * 64 + (p >> 3);
    const int bx = q_ & 7, bh = q_ >> 3;
    const int b = bh >> 4, h = bh & 15;
    const int qb = bx * 256 + w * 64;           // this wave's 64 q-rows

    const int srow = w * 16 + (lane >> 3);
    const int swz  = ((lane & 7) ^ (lane >> 3)) * 8;

    const unsigned short* Kg0 = Km + (size_t)(b * 2048 + srow) * 1024 + h * 64 + swz;
    const unsigned short* Vg0 = VT + ((size_t)bh * 64 + srow) * 2048 + swz;

    bf16x8 qf[2][4];
#pragma unroll
    for (int s = 0; s < 2; ++s)
#pragma unroll
        for (int f = 0; f < 4; ++f)
            qf[s][f] = *(const bf16x8*)&Q[(size_t)(b * 2048 + qb + s * 32 + li5) * 1024
                                          + h * 64 + f * 16 + l5 * 8];

    f32x16 acc[2][2] = {};
    float ls00 = 0.f, ls01 = 0.f, ls10 = 0.f, ls11 = 0.f;

    // prologue: stage super-tile 0 (j = 0..127) into dbuf 0
#pragma unroll
    for (int t2 = 0; t2 < 2; ++t2)
#pragma unroll
        for (int it = 0; it < 2; ++it) {
            gl2lds16(Kg0 + (size_t)(t2 * 64 + it * 8) * 1024,
                     &Ks[0][t2 * 4096 + (w * 2 + it) * 512]);
            gl2lds16(Vg0 + (size_t)(it * 8) * 2048 + t2 * 64,
                     &Vs[0][t2 * 4096 + (w * 2 + it) * 512]);
        }
    __syncthreads();

    for (int tb = 0; tb < 16; ++tb) {
        const int buf = tb & 1;
        if (tb < 15) {
            const int j1 = tb * 128 + 128;
#pragma unroll
            for (int t2 = 0; t2 < 2; ++t2)
#pragma unroll
                for (int it = 0; it < 2; ++it) {
                    gl2lds16(Kg0 + (size_t)(j1 + t2 * 64 + it * 8) * 1024,
                             &Ks[buf ^ 1][t2 * 4096 + (w * 2 + it) * 512]);
                    gl2lds16(Vg0 + (size_t)(it * 8) * 2048 + j1 + t2 * 64,
                             &Vs[buf ^ 1][t2 * 4096 + (w * 2 + it) * 512]);
                }
        }

#pragma unroll
        for (int sub = 0; sub < 2; ++sub) {
            const int j0 = tb * 128 + sub * 64;
            const int sb = sub * 4096;

            // K fragments, shared by both q-sets
            bf16x8 kf[2][4];
#pragma unroll
            for (int jf = 0; jf < 2; ++jf)
#pragma unroll
                for (int f = 0; f < 4; ++f)
                    kf[jf][f] = *(const bf16x8*)&Ks[buf][sb + (jf * 32 + li5) * 64
                                                         + ((f * 2 + l5) ^ li7) * 8];

            unsigned pw[2][2][8];
#pragma unroll
            for (int s = 0; s < 2; ++s) {
                f32x16 st[2];
                __builtin_amdgcn_s_setprio(1);
#pragma unroll
                for (int jf = 0; jf < 2; ++jf) {
                    f32x16 z = {};
#pragma unroll
                    for (int f = 0; f < 4; ++f)
                        z = __builtin_amdgcn_mfma_f32_32x32x16_bf16(kf[jf][f], qf[s][f], z, 0, 0, 0);
                    st[jf] = z;
                }
                __builtin_amdgcn_s_setprio(0);

                const int qbs = qb + s * 32;
                if (j0 >= qbs - 65 && j0 <= qbs + 33) {
#pragma unroll
                    for (int jf = 0; jf < 2; ++jf)
#pragma unroll
                        for (int r = 0; r < 16; ++r) {
                            int j = j0 + jf * 32 + (r & 3) + 8 * (r >> 2) + 4 * l5;
                            int dq = (qbs + li5) - j;
                            if ((unsigned)(dq + 2) <= 4u) st[jf][r] += 0.1f * L2E;
                        }
                }

                // exp2 + cvt_pk pack
#pragma unroll
                for (int jf = 0; jf < 2; ++jf)
#pragma unroll
                    for (int m = 0; m < 8; ++m) {
                        float p0 = __builtin_amdgcn_exp2f(st[jf][2 * m]);
                        float p1 = __builtin_amdgcn_exp2f(st[jf][2 * m + 1]);
                        float pp = p0 + p1;
                        if (s == 0) { if (m & 1) ls01 += pp; else ls00 += pp; }
                        else        { if (m & 1) ls11 += pp; else ls10 += pp; }
                        asm("v_cvt_pk_bf16_f32 %0, %1, %2"
                            : "=v"(pw[s][jf][m]) : "v"(p0), "v"(p1));
                    }

                // single-transposition redistribution: 8 x permlane32_swap
#pragma unroll
                for (int jf = 0; jf < 2; ++jf)
#pragma unroll
                    for (int m2 = 0; m2 < 2; ++m2)
#pragma unroll
                        for (int m0_ = 0; m0_ < 2; ++m0_) {
                            unsigned a0 = pw[s][jf][m2 * 4 + m0_];
                            unsigned b0 = pw[s][jf][m2 * 4 + m0_ + 2];
                            asm volatile("v_permlane32_swap_b32 %0, %1"
                                         : "+v"(a0), "+v"(b0));
                            pw[s][jf][m2 * 4 + m0_]     = a0;
                            pw[s][jf][m2 * 4 + m0_ + 2] = b0;
                        }
            }

            // PV: V fragments shared by both sets
            __builtin_amdgcn_s_setprio(1);
#pragma unroll
            for (int db = 0; db < 2; ++db)
#pragma unroll
                for (int tt = 0; tt < 4; ++tt) {
                    bf16x8 vf = *(const bf16x8*)&Vs[buf][sb + (db * 32 + li5) * 64
                                                         + ((tt * 2 + l5) ^ li7) * 8];
                    const int jf = tt >> 1, m2 = tt & 1;
#pragma unroll
                    for (int s = 0; s < 2; ++s) {
                        u32x4 tw = {pw[s][jf][m2 * 4 + 0], pw[s][jf][m2 * 4 + 1],
                                    pw[s][jf][m2 * 4 + 2], pw[s][jf][m2 * 4 + 3]};
                        acc[s][db] = __builtin_amdgcn_mfma_f32_32x32x16_bf16(
                            vf, __builtin_bit_cast(bf16x8, tw), acc[s][db], 0, 0, 0);
                    }
                }
            __builtin_amdgcn_s_setprio(0);
        }
        __syncthreads();
    }

#pragma unroll
    for (int s = 0; s < 2; ++s) {
        float lr = s == 0 ? (ls00 + ls01) : (ls10 + ls11);
        float l2 = lr + __shfl_xor(lr, 32);
        const float inv = 1.f / l2;
        const int qrow = qb + s * 32 + li5;
#pragma unroll
        for (int db = 0; db < 2; ++db)
#pragma unroll
            for (int g = 0; g < 4; ++g) {
                ushort4 o;
                o.x = f2bf(acc[s][db][g * 4 + 0] * inv);
                o.y = f2bf(acc[s][db][g * 4 + 1] * inv);
                o.z = f2bf(acc[s][db][g * 4 + 2] * inv);
                o.w = f2bf(acc[s][db][g * 4 + 3] * inv);
                *(ushort4*)&AO[(size_t)(b * 2048 + qrow) * 1024 + h * 64
                               + db * 32 + g * 8 + l5 * 4] = o;
            }
    }
}

// ---------------- launch ----------------
extern "C" void kernel_launch(void* const* d_in, const int* in_sizes, int n_in,
                              void* d_out, int out_size, void* d_ws, size_t ws_size,
                              hipStream_t stream) {
    const float* x   = (const float*)d_in[0];
    const float* Wq  = (const float*)d_in[2];
    const float* bq  = (const float*)d_in[3];
    const float* Wk  = (const float*)d_in[4];
    const float* bk  = (const float*)d_in[5];
    const float* Wv  = (const float*)d_in[6];
    const float* bv  = (const float*)d_in[7];
    const float* Wo  = (const float*)d_in[8];
    const float* bo  = (const float*)d_in[9];
    const float* ocr = (const float*)d_in[10];
    float* out = (float*)d_out;

    char* ws = (char*)d_ws;
    const size_t MB = 1024 * 1024;
    unsigned short* xb  = (unsigned short*)(ws);            // 16 MB (reused as AO)
    unsigned short* Wqb = (unsigned short*)(ws + 16 * MB);  // 2 MB each
    unsigned short* Wkb = (unsigned short*)(ws + 18 * MB);
    unsigned short* Wvb = (unsigned short*)(ws + 20 * MB);
    unsigned short* Wob = (unsigned short*)(ws + 22 * MB);
    unsigned short* Qb  = (unsigned short*)(ws + 24 * MB);  // 16 MB
    unsigned short* Kb  = (unsigned short*)(ws + 40 * MB);  // 16 MB
    unsigned short* VTb = (unsigned short*)(ws + 56 * MB);  // 16 MB, [bh][d][s]
    unsigned short* AO  = xb;  // x dead after projections

    cast_all<<<3072, 256, 0, stream>>>(x, Wq, Wk, Wv, Wo,
                                       xb, Wqb, Wkb, Wvb, Wob);

    const float QSC = 0.125f * L2E;  // fold 1/sqrt(64) and log2(e) into Q
    qkv_gemm<<<dim3(24, 64), 256, 0, stream>>>(xb, Wqb, Wkb, Wvb,
                                               bq, bk, bv, ocr, QSC,
                                               Qb, Kb, VTb);

    attn_kernel<<<dim3(8, 64), 256, 0, stream>>>(Qb, Kb, VTb, AO);

    out_gemm<<<dim3(8, 64), 256, 0, stream>>>(AO, Wob, bo, out);
}

// Round 11
// 203.702 us; speedup vs baseline: 1.9509x; 1.4484x over previous
//
#include <hip/hip_runtime.h>
#include <hip/hip_bf16.h>
#include <stdint.h>

typedef __attribute__((ext_vector_type(8))) short bf16x8;
typedef __attribute__((ext_vector_type(4))) float f32x4;
typedef __attribute__((ext_vector_type(16))) float f32x16;
typedef __attribute__((ext_vector_type(4))) unsigned u32x4;

#define L2E 1.4426950408889634f

static __device__ __forceinline__ unsigned short f2bf(float f) {
    __hip_bfloat16 h = __float2bfloat16(f);
    return __builtin_bit_cast(unsigned short, h);
}

static __device__ __forceinline__ void gl2lds16(const void* g, void* l) {
    __builtin_amdgcn_global_load_lds(
        (const __attribute__((address_space(1))) void*)g,
        (__attribute__((address_space(3))) void*)l,
        16, 0, 0);
}

// ---------------- all casts fp32 -> bf16, one dispatch ----------------
__global__ void cast_all(const float* __restrict__ x,
                         const float* __restrict__ Wq, const float* __restrict__ Wk,
                         const float* __restrict__ Wv, const float* __restrict__ Wo,
                         unsigned short* __restrict__ xb,
                         unsigned short* __restrict__ Wqb, unsigned short* __restrict__ Wkb,
                         unsigned short* __restrict__ Wvb, unsigned short* __restrict__ Wob) {
    int i = blockIdx.x * blockDim.x + threadIdx.x;
    const int stride = gridDim.x * blockDim.x;
    for (; i < 3145728; i += stride) {
        const float* src; unsigned short* dst; int k;
        if (i < 2097152) { src = x; dst = xb; k = i; }
        else {
            int j = i - 2097152; int m = j >> 18; k = j & 262143;
            src = m == 0 ? Wq : m == 1 ? Wk : m == 2 ? Wv : Wo;
            dst = m == 0 ? Wqb : m == 1 ? Wkb : m == 2 ? Wvb : Wob;
        }
        float4 v = ((const float4*)src)[k];
        ushort4 o;
        o.x = f2bf(v.x); o.y = f2bf(v.y); o.z = f2bf(v.z); o.w = f2bf(v.w);
        ((ushort4*)dst)[k] = o;
    }
}

// ---------------- fused QKV projection GEMM ----------------
__global__ __launch_bounds__(256) void qkv_gemm(
    const unsigned short* __restrict__ A,
    const unsigned short* __restrict__ Wq,
    const unsigned short* __restrict__ Wk,
    const unsigned short* __restrict__ Wv,
    const float* __restrict__ bq,
    const float* __restrict__ bk,
    const float* __restrict__ bv,
    const float* __restrict__ ocr,
    float qscale,
    unsigned short* __restrict__ Qo,
    unsigned short* __restrict__ Ko,
    unsigned short* __restrict__ VTo)
{
    constexpr int K = 1024;
    __shared__ __align__(16) unsigned short SMEM[16384];   // 32 KB, reused in epilogue
    unsigned short (*As)[64] = (unsigned short(*)[64])SMEM;
    unsigned short (*Bs)[64] = (unsigned short(*)[64])(SMEM + 8192);

    const int tid  = threadIdx.x;
    const int wave = tid >> 6, lane = tid & 63;
    const int li = lane & 15, lg = lane >> 4;

    const int lin = blockIdx.y * 24 + blockIdx.x;
    const int n2  = (lin & 7) * 192 + (lin >> 3);   // XCD-chunked, bijective
    const int mb = n2 / 24, nbb = n2 - mb * 24;
    const int proj = nbb >> 3;
    const int m0 = mb * 128, n0 = (nbb & 7) * 128;

    const unsigned short* W = proj == 0 ? Wq : proj == 1 ? Wk : Wv;
    const float* bias = proj == 0 ? bq : proj == 1 ? bk : bv;

    const int wm = (wave >> 1) * 64, wn = (wave & 1) * 64;
    const int srow = wave * 8 + (lane >> 3);
    const int scol = (lane & 7) * 8;

    f32x4 acc[4][4] = {};

    for (int k0 = 0; k0 < K; k0 += 64) {
#pragma unroll
        for (int rnd = 0; rnd < 4; ++rnd)
            gl2lds16(A + (size_t)(m0 + rnd * 32 + srow) * K + k0 + scol,
                     &As[rnd * 32 + wave * 8][0]);
#pragma unroll
        for (int rnd = 0; rnd < 4; ++rnd)
            gl2lds16(W + (size_t)(n0 + rnd * 32 + srow) * K + k0 + scol,
                     &Bs[rnd * 32 + wave * 8][0]);
        __syncthreads();
#pragma unroll
        for (int kk = 0; kk < 64; kk += 32) {
            bf16x8 af[4], bfr[4];
#pragma unroll
            for (int m = 0; m < 4; ++m)
                af[m] = *(const bf16x8*)&As[wm + m * 16 + li][kk + lg * 8];
#pragma unroll
            for (int n = 0; n < 4; ++n)
                bfr[n] = *(const bf16x8*)&Bs[wn + n * 16 + li][kk + lg * 8];
#pragma unroll
            for (int m = 0; m < 4; ++m)
#pragma unroll
                for (int n = 0; n < 4; ++n)
                    acc[m][n] = __builtin_amdgcn_mfma_f32_16x16x32_bf16(
                        af[m], bfr[n], acc[m][n], 0, 0, 0);
        }
        __syncthreads();
    }

    if (proj == 2) {
#pragma unroll
        for (int n = 0; n < 4; ++n) {
            const int dl = wn + n * 16 + li;
            const float bb = bias[n0 + dl];
#pragma unroll
            for (int m = 0; m < 4; ++m) {
                const int sl = wm + m * 16 + lg * 4;
                const int unit = (sl >> 2) ^ (dl & 7);
                ushort4 o;
                o.x = f2bf(acc[m][n][0] + bb);
                o.y = f2bf(acc[m][n][1] + bb);
                o.z = f2bf(acc[m][n][2] + bb);
                o.w = f2bf(acc[m][n][3] + bb);
                *(ushort4*)&SMEM[dl * 128 + unit * 4] = o;
            }
        }
        __syncthreads();
        const int s2 = (lane & 15) * 8;
        const int u0b = s2 >> 2;
#pragma unroll
        for (int k = 0; k < 8; ++k) {
            const int dl = wave * 32 + k * 4 + (lane >> 4);
            const int u0 = u0b ^ (dl & 7);
            const int u1 = (u0b + 1) ^ (dl & 7);
            uint2 lo = *(uint2*)&SMEM[dl * 128 + u0 * 4];
            uint2 hi = *(uint2*)&SMEM[dl * 128 + u1 * 4];
            const int col = n0 + dl;
            const int bh2 = ((m0 >> 11) << 4) + (col >> 6);
            uint4 o4;
            o4.x = lo.x; o4.y = lo.y; o4.z = hi.x; o4.w = hi.y;
            *(uint4*)&VTo[((size_t)bh2 * 64 + (col & 63)) * 2048 + (m0 & 2047) + s2] = o4;
        }
    } else {
        const float scale = proj == 0 ? qscale : 1.f;
        unsigned short* dst = proj == 0 ? Qo : Ko;
#pragma unroll
        for (int n = 0; n < 4; ++n) {
            const int col = n0 + wn + n * 16 + li;
            float bb = bias[col];
            if (proj == 0) bb += ocr[col];
#pragma unroll
            for (int m = 0; m < 4; ++m)
#pragma unroll
                for (int r = 0; r < 4; ++r) {
                    const int row = m0 + wm + m * 16 + lg * 4 + r;
                    dst[(size_t)row * 1024 + col] = f2bf((acc[m][n][r] + bb) * scale);
                }
        }
    }
}

// ---------------- output projection GEMM (f32 out) ----------------
__global__ __launch_bounds__(256) void out_gemm(
    const unsigned short* __restrict__ A,
    const unsigned short* __restrict__ W,
    const float* __restrict__ bias,
    float* __restrict__ of)
{
    constexpr int K = 1024;
    __shared__ unsigned short As[128][64];
    __shared__ unsigned short Bs[128][64];

    const int tid  = threadIdx.x;
    const int wave = tid >> 6, lane = tid & 63;
    const int li = lane & 15, lg = lane >> 4;
    const int lin = blockIdx.y * 8 + blockIdx.x;
    const int n2  = (lin & 7) * 64 + (lin >> 3);
    const int m0 = (n2 >> 3) * 128, n0 = (n2 & 7) * 128;
    const int wm = (wave >> 1) * 64, wn = (wave & 1) * 64;

    const int srow = wave * 8 + (lane >> 3);
    const int scol = (lane & 7) * 8;

    f32x4 acc[4][4] = {};

    for (int k0 = 0; k0 < K; k0 += 64) {
#pragma unroll
        for (int rnd = 0; rnd < 4; ++rnd)
            gl2lds16(A + (size_t)(m0 + rnd * 32 + srow) * K + k0 + scol,
                     &As[rnd * 32 + wave * 8][0]);
#pragma unroll
        for (int rnd = 0; rnd < 4; ++rnd)
            gl2lds16(W + (size_t)(n0 + rnd * 32 + srow) * K + k0 + scol,
                     &Bs[rnd * 32 + wave * 8][0]);
        __syncthreads();
#pragma unroll
        for (int kk = 0; kk < 64; kk += 32) {
            bf16x8 af[4], bfr[4];
#pragma unroll
            for (int m = 0; m < 4; ++m)
                af[m] = *(const bf16x8*)&As[wm + m * 16 + li][kk + lg * 8];
#pragma unroll
            for (int n = 0; n < 4; ++n)
                bfr[n] = *(const bf16x8*)&Bs[wn + n * 16 + li][kk + lg * 8];
#pragma unroll
            for (int m = 0; m < 4; ++m)
#pragma unroll
                for (int n = 0; n < 4; ++n)
                    acc[m][n] = __builtin_amdgcn_mfma_f32_16x16x32_bf16(
                        af[m], bfr[n], acc[m][n], 0, 0, 0);
        }
        __syncthreads();
    }

#pragma unroll
    for (int n = 0; n < 4; ++n) {
        const int col = n0 + wn + n * 16 + li;
        const float bb = bias[col];
#pragma unroll
        for (int m = 0; m < 4; ++m)
#pragma unroll
            for (int r = 0; r < 4; ++r) {
                const int row = m0 + wm + m * 16 + lg * 4 + r;
                of[(size_t)row * 1024 + col] = acc[m][n][r] + bb;
            }
    }
}

// ---------------- fused flash attention (32x32x16 MFMA, 2 q-sets/wave) -----
// EXACT round-6 kernel (measured: 91 us, VGPR 120, zero scratch).
__global__ __launch_bounds__(256, 2) void attn_kernel(
    const unsigned short* __restrict__ Q,
    const unsigned short* __restrict__ Km,
    const unsigned short* __restrict__ VT,
    unsigned short* __restrict__ AO)
{
    __shared__ unsigned short Ks[2][4096];      // [buf][64 j][64 d] 16B-chunk XOR-swz
    __shared__ unsigned short Vs[2][4096];      // [buf][64 d][64 j] 16B-chunk XOR-swz

    const int tid  = threadIdx.x;
    const int w = tid >> 6, lane = tid & 63;
    const int li5 = lane & 31, l5 = lane >> 5, li7 = li5 & 7;

    // bijective XCD-chunked remap over 512 blocks (8 x 64 grid)
    const int p  = blockIdx.y * 8 + blockIdx.x;
    const int q_ = (p & 7) * 64 + (p >> 3);
    const int bx = q_ & 7, bh = q_ >> 3;
    const int b = bh >> 4, h = bh & 15;
    const int qb = bx * 256 + w * 64;           // this wave's 64 q-rows

    const int srow = w * 16 + (lane >> 3);
    const int swz  = ((lane & 7) ^ (lane >> 3)) * 8;

    const unsigned short* Kg0 = Km + (size_t)(b * 2048 + srow) * 1024 + h * 64 + swz;
    const unsigned short* Vg0 = VT + ((size_t)bh * 64 + srow) * 2048 + swz;

    bf16x8 qf[2][4];
#pragma unroll
    for (int s = 0; s < 2; ++s)
#pragma unroll
        for (int f = 0; f < 4; ++f)
            qf[s][f] = *(const bf16x8*)&Q[(size_t)(b * 2048 + qb + s * 32 + li5) * 1024
                                          + h * 64 + f * 16 + l5 * 8];

    f32x16 acc[2][2] = {};
    float ls00 = 0.f, ls01 = 0.f, ls10 = 0.f, ls11 = 0.f;

#pragma unroll
    for (int it = 0; it < 2; ++it) {
        gl2lds16(Kg0 + (size_t)(it * 8) * 1024, &Ks[0][(w * 2 + it) * 512]);
        gl2lds16(Vg0 + (size_t)(it * 8) * 2048, &Vs[0][(w * 2 + it) * 512]);
    }
    __syncthreads();

    for (int t = 0; t < 32; ++t) {
        const int buf = t & 1;
        const int j0 = t * 64;
        if (t < 31) {
            const int j1 = j0 + 64;
#pragma unroll
            for (int it = 0; it < 2; ++it) {
                gl2lds16(Kg0 + (size_t)(j1 + it * 8) * 1024, &Ks[buf ^ 1][(w * 2 + it) * 512]);
                gl2lds16(Vg0 + (size_t)(it * 8) * 2048 + j1, &Vs[buf ^ 1][(w * 2 + it) * 512]);
            }
        }

        // K fragments, shared by both q-sets
        bf16x8 kf[2][4];
#pragma unroll
        for (int jf = 0; jf < 2; ++jf)
#pragma unroll
            for (int f = 0; f < 4; ++f)
                kf[jf][f] = *(const bf16x8*)&Ks[buf][(jf * 32 + li5) * 64
                                                     + ((f * 2 + l5) ^ li7) * 8];

        unsigned pw[2][2][8];
#pragma unroll
        for (int s = 0; s < 2; ++s) {
            // QK^T: st[jf][reg] = S[q][j = j0 + jf*32 + (reg&3) + 8*(reg>>2) + 4*l5]
            f32x16 st[2];
            __builtin_amdgcn_s_setprio(1);
#pragma unroll
            for (int jf = 0; jf < 2; ++jf) {
                f32x16 z = {};
#pragma unroll
                for (int f = 0; f < 4; ++f)
                    z = __builtin_amdgcn_mfma_f32_32x32x16_bf16(kf[jf][f], qf[s][f], z, 0, 0, 0);
                st[jf] = z;
            }
            __builtin_amdgcn_s_setprio(0);

            const int qbs = qb + s * 32;
            if (j0 >= qbs - 65 && j0 <= qbs + 33) {
#pragma unroll
                for (int jf = 0; jf < 2; ++jf)
#pragma unroll
                    for (int r = 0; r < 16; ++r) {
                        int j = j0 + jf * 32 + (r & 3) + 8 * (r >> 2) + 4 * l5;
                        int dq = (qbs + li5) - j;
                        if ((unsigned)(dq + 2) <= 4u) st[jf][r] += 0.1f * L2E;
                    }
            }

            // exp2 + cvt_pk pack
#pragma unroll
            for (int jf = 0; jf < 2; ++jf)
#pragma unroll
                for (int m = 0; m < 8; ++m) {
                    float p0 = __builtin_amdgcn_exp2f(st[jf][2 * m]);
                    float p1 = __builtin_amdgcn_exp2f(st[jf][2 * m + 1]);
                    float pp = p0 + p1;
                    if (s == 0) { if (m & 1) ls01 += pp; else ls00 += pp; }
                    else        { if (m & 1) ls11 += pp; else ls10 += pp; }
                    asm("v_cvt_pk_bf16_f32 %0, %1, %2"
                        : "=v"(pw[s][jf][m]) : "v"(p0), "v"(p1));
                }

            // single-transposition redistribution: 8 x permlane32_swap
#pragma unroll
            for (int jf = 0; jf < 2; ++jf)
#pragma unroll
                for (int m2 = 0; m2 < 2; ++m2)
#pragma unroll
                    for (int m0_ = 0; m0_ < 2; ++m0_) {
                        unsigned a0 = pw[s][jf][m2 * 4 + m0_];
                        unsigned b0 = pw[s][jf][m2 * 4 + m0_ + 2];
                        asm volatile("v_permlane32_swap_b32 %0, %1"
                                     : "+v"(a0), "+v"(b0));
                        pw[s][jf][m2 * 4 + m0_]     = a0;
                        pw[s][jf][m2 * 4 + m0_ + 2] = b0;
                    }
        }

        // PV: V fragments shared by both sets
        __builtin_amdgcn_s_setprio(1);
#pragma unroll
        for (int db = 0; db < 2; ++db)
#pragma unroll
            for (int tt = 0; tt < 4; ++tt) {
                bf16x8 vf = *(const bf16x8*)&Vs[buf][(db * 32 + li5) * 64
                                                     + ((tt * 2 + l5) ^ li7) * 8];
                const int jf = tt >> 1, m2 = tt & 1;
#pragma unroll
                for (int s = 0; s < 2; ++s) {
                    u32x4 tw = {pw[s][jf][m2 * 4 + 0], pw[s][jf][m2 * 4 + 1],
                                pw[s][jf][m2 * 4 + 2], pw[s][jf][m2 * 4 + 3]};
                    acc[s][db] = __builtin_amdgcn_mfma_f32_32x32x16_bf16(
                        vf, __builtin_bit_cast(bf16x8, tw), acc[s][db], 0, 0, 0);
                }
            }
        __builtin_amdgcn_s_setprio(0);
        __syncthreads();
    }

#pragma unroll
    for (int s = 0; s < 2; ++s) {
        float lr = s == 0 ? (ls00 + ls01) : (ls10 + ls11);
        float l2 = lr + __shfl_xor(lr, 32);
        const float inv = 1.f / l2;
        const int qrow = qb + s * 32 + li5;
#pragma unroll
        for (int db = 0; db < 2; ++db)
#pragma unroll
            for (int g = 0; g < 4; ++g) {
                ushort4 o;
                o.x = f2bf(acc[s][db][g * 4 + 0] * inv);
                o.y = f2bf(acc[s][db][g * 4 + 1] * inv);
                o.z = f2bf(acc[s][db][g * 4 + 2] * inv);
                o.w = f2bf(acc[s][db][g * 4 + 3] * inv);
                *(ushort4*)&AO[(size_t)(b * 2048 + qrow) * 1024 + h * 64
                               + db * 32 + g * 8 + l5 * 4] = o;
            }
    }
}

// ---------------- launch ----------------
extern "C" void kernel_launch(void* const* d_in, const int* in_sizes, int n_in,
                              void* d_out, int out_size, void* d_ws, size_t ws_size,
                              hipStream_t stream) {
    const float* x   = (const float*)d_in[0];
    const float* Wq  = (const float*)d_in[2];
    const float* bq  = (const float*)d_in[3];
    const float* Wk  = (const float*)d_in[4];
    const float* bk  = (const float*)d_in[5];
    const float* Wv  = (const float*)d_in[6];
    const float* bv  = (const float*)d_in[7];
    const float* Wo  = (const float*)d_in[8];
    const float* bo  = (const float*)d_in[9];
    const float* ocr = (const float*)d_in[10];
    float* out = (float*)d_out;

    char* ws = (char*)d_ws;
    const size_t MB = 1024 * 1024;
    unsigned short* xb  = (unsigned short*)(ws);            // 16 MB (reused as AO)
    unsigned short* Wqb = (unsigned short*)(ws + 16 * MB);  // 2 MB each
    unsigned short* Wkb = (unsigned short*)(ws + 18 * MB);
    unsigned short* Wvb = (unsigned short*)(ws + 20 * MB);
    unsigned short* Wob = (unsigned short*)(ws + 22 * MB);
    unsigned short* Qb  = (unsigned short*)(ws + 24 * MB);  // 16 MB
    unsigned short* Kb  = (unsigned short*)(ws + 40 * MB);  // 16 MB
    unsigned short* VTb = (unsigned short*)(ws + 56 * MB);  // 16 MB, [bh][d][s]
    unsigned short* AO  = xb;  // x dead after projections

    cast_all<<<3072, 256, 0, stream>>>(x, Wq, Wk, Wv, Wo,
                                       xb, Wqb, Wkb, Wvb, Wob);

    const float QSC = 0.125f * L2E;  // fold 1/sqrt(64) and log2(e) into Q
    qkv_gemm<<<dim3(24, 64), 256, 0, stream>>>(xb, Wqb, Wkb, Wvb,
                                               bq, bk, bv, ocr, QSC,
                                               Qb, Kb, VTb);

    attn_kernel<<<dim3(8, 64), 256, 0, stream>>>(Qb, Kb, VTb, AO);

    out_gemm<<<dim3(8, 64), 256, 0, stream>>>(AO, Wob, bo, out);
}